// Round 1
// baseline (655.833 us; speedup 1.0000x reference)
//
#include <hip/hip_runtime.h>

// TwelveSitesNN2: fused fp32 kernel, one block = (one l, 16 b's), 256 threads.
// L=63, S=12, B=2048. Layer2 (K=96 -> 64) dominates: 9.5G of 11.4G MACs.

#define BT 16
#define NBT 128  // 2048 / BT
#define LNUM 63

__device__ __forceinline__ unsigned f2bf(float f) {
    unsigned u = __float_as_uint(f);
    return (u + 0x7fffu + ((u >> 16) & 1u)) >> 16;   // RNE bf16
}
__device__ __forceinline__ unsigned pack2(float a, float b) {
    return f2bf(a) | (f2bf(b) << 16);
}
__device__ __forceinline__ float bflo(unsigned u) { return __uint_as_float(u << 16); }
__device__ __forceinline__ float bfhi(unsigned u) { return __uint_as_float(u & 0xffff0000u); }
__device__ __forceinline__ int w12(int v) { return v >= 12 ? v - 12 : v; }

__global__ __launch_bounds__(256, 2) void fused_nn(
    const float* __restrict__ zs,  const float* __restrict__ w1,  const float* __restrict__ w2,
    const float* __restrict__ fw1, const float* __restrict__ fb1,
    const float* __restrict__ fw2, const float* __restrict__ fb2,
    const float* __restrict__ fw3, const float* __restrict__ fb3,
    float* __restrict__ out)
{
    __shared__ __align__(16) float    s_w1[192];      // [c<6][o<32]
    __shared__ __align__(16) unsigned s_fw1u[4096];   // bf16x2, [c<128][o<64]; later g1/g2 fp32
    __shared__ __align__(16) unsigned s_fw2u[2048];   // bf16x2, [c<64][o<64]
    __shared__ __align__(16) float    s_fw3[64];
    __shared__ __align__(16) float    s_fb1[64];
    __shared__ __align__(16) float    s_fb2[64];
    __shared__ float                  s_fb3v[1];
    __shared__ __align__(16) float    s_x[BT * 24];   // [b][s][ch]
    // Union region (49920B):
    //  phase1-2: w2 fp32 [0..6143] ([c<96][o<64]) | h1 fp32 [6144..12479] (192 rows, stride 33)
    //  post-2  : h2 bf16 overlays h1 slot (192 rows x 32 uints, stride 33 uints)
    //  pooling : pooled fp32 [0..2047] (16 b x 128) overlays w2
    __shared__ __align__(16) float    s_U[12480];

    const int t  = threadIdx.x;
    const int l  = blockIdx.x / NBT;
    const int b0 = (blockIdx.x % NBT) * BT;

    // ---------------- stage weights + x ----------------
    {
        const float4* g2v = (const float4*)(w2 + (size_t)l * 6144);
        float4* u4 = (float4*)s_U;
        #pragma unroll
        for (int k = 0; k < 6; ++k) u4[t + k * 256] = g2v[t + k * 256];

        const float4* g1v = (const float4*)(fw1 + (size_t)l * 8192);
        #pragma unroll
        for (int k = 0; k < 8; ++k) {
            int i = t + k * 256;
            float4 f = g1v[i];
            s_fw1u[2 * i]     = pack2(f.x, f.y);
            s_fw1u[2 * i + 1] = pack2(f.z, f.w);
        }
        const float4* g2w = (const float4*)(fw2 + (size_t)l * 4096);
        #pragma unroll
        for (int k = 0; k < 4; ++k) {
            int i = t + k * 256;
            float4 f = g2w[i];
            s_fw2u[2 * i]     = pack2(f.x, f.y);
            s_fw2u[2 * i + 1] = pack2(f.z, f.w);
        }
        if (t < 96) {  // x tile: 16 b x 24 floats = 96 float4
            int b = t / 6, q = t - 6 * b;
            float4 f = *(const float4*)(zs + ((size_t)(b0 + b) * LNUM + l) * 24 + q * 4);
            *(float4*)(s_x + b * 24 + q * 4) = f;
        }
        if (t < 48) ((float4*)s_w1)[t] = ((const float4*)(w1 + (size_t)l * 192))[t];
        if (t >= 96 && t < 112)  ((float4*)s_fw3)[t - 96]  = ((const float4*)(fw3 + (size_t)l * 64))[t - 96];
        if (t >= 112 && t < 128) ((float4*)s_fb1)[t - 112] = ((const float4*)(fb1 + (size_t)l * 64))[t - 112];
        if (t >= 128 && t < 144) ((float4*)s_fb2)[t - 128] = ((const float4*)(fb2 + (size_t)l * 64))[t - 128];
        if (t == 144) s_fb3v[0] = fb3[l];
    }
    __syncthreads();

    // ---------------- layer 1: h1 (192 rows x 32), K=6 ----------------
    // allc1 channels: [x(2), A(2), B(2)];  A(s)=x[s+1]+x[s-3]+x[s+3]+x[s-1], B(s)=x[s+2]+x[s-4]+x[s+4]+x[s-2]
    #pragma unroll
    for (int p = 0; p < 2; ++p) {
        int u = t + p * 256;
        if (u < 384) {
            int row = u >> 1;
            int b = row / 12, s = row - 12 * b;
            int ob = (u & 1) * 16;
            const float* xb = s_x + b * 24;
            int sA1 = w12(s + 1), sA2 = w12(s + 9),  sA3 = w12(s + 3), sA4 = w12(s + 11);
            int sB1 = w12(s + 2), sB2 = w12(s + 8),  sB3 = w12(s + 4), sB4 = w12(s + 10);
            float a0 = xb[s * 2],     a1 = xb[s * 2 + 1];
            float a2 = xb[sA1*2]   + xb[sA2*2]   + xb[sA3*2]   + xb[sA4*2];
            float a3 = xb[sA1*2+1] + xb[sA2*2+1] + xb[sA3*2+1] + xb[sA4*2+1];
            float a4 = xb[sB1*2]   + xb[sB2*2]   + xb[sB3*2]   + xb[sB4*2];
            float a5 = xb[sB1*2+1] + xb[sB2*2+1] + xb[sB3*2+1] + xb[sB4*2+1];
            float* h1r = s_U + 6144 + row * 33;
            #pragma unroll
            for (int j = 0; j < 16; ++j) {
                int o = ob + j;
                float h = a0 * s_w1[o]       + a1 * s_w1[32 + o]  + a2 * s_w1[64 + o]
                        + a3 * s_w1[96 + o]  + a4 * s_w1[128 + o] + a5 * s_w1[160 + o];
                h1r[o] = fmaxf(h, 0.f);
            }
        }
    }
    __syncthreads();

    // ---------------- layer 2: h2 (192 rows x 64), K=96 — the hot loop ----------------
    float acc[2][32];
    #pragma unroll
    for (int p = 0; p < 2; ++p)
        #pragma unroll
        for (int j = 0; j < 32; ++j) acc[p][j] = 0.f;

    #pragma unroll
    for (int p = 0; p < 2; ++p) {
        int u = t + p * 256;
        if (u < 384) {
            int row = u >> 1;
            int b = row / 12, s = row - 12 * b;
            int ob = (u & 1) * 32;
            const float* h1b = s_U + 6144;
            int rb = b * 12;
            int o0  = (rb + s) * 33;
            int oA1 = (rb + w12(s + 1)) * 33, oA2 = (rb + w12(s + 9)) * 33;
            int oA3 = (rb + w12(s + 3)) * 33, oA4 = (rb + w12(s + 11)) * 33;
            int oB1 = (rb + w12(s + 2)) * 33, oB2 = (rb + w12(s + 8)) * 33;
            int oB3 = (rb + w12(s + 4)) * 33, oB4 = (rb + w12(s + 10)) * 33;
            for (int c = 0; c < 32; ++c) {
                float a0 = h1b[o0 + c];
                float a1 = h1b[oA1 + c] + h1b[oA2 + c] + h1b[oA3 + c] + h1b[oA4 + c];
                float a2 = h1b[oB1 + c] + h1b[oB2 + c] + h1b[oB3 + c] + h1b[oB4 + c];
                const float* wr0 = s_U + c * 64 + ob;   // w2 row c    (broadcast b128s)
                const float* wr1 = wr0 + 2048;          // row 32+c
                const float* wr2 = wr0 + 4096;          // row 64+c
                #pragma unroll
                for (int j = 0; j < 32; ++j)
                    acc[p][j] += a0 * wr0[j] + a1 * wr1[j] + a2 * wr2[j];
            }
        }
    }
    __syncthreads();   // all h1 / w2 reads done; safe to overlay

    // relu + store h2 as bf16 into the h1 slot (stride 33 uints per row)
    unsigned* h2u = (unsigned*)(s_U + 6144);
    #pragma unroll
    for (int p = 0; p < 2; ++p) {
        int u = t + p * 256;
        if (u < 384) {
            int row = u >> 1;
            int ob = (u & 1) * 32;
            #pragma unroll
            for (int j = 0; j < 16; ++j) {
                float e = fmaxf(acc[p][2 * j], 0.f);
                float o = fmaxf(acc[p][2 * j + 1], 0.f);
                h2u[row * 33 + (ob >> 1) + j] = pack2(e, o);
            }
        }
    }
    __syncthreads();

    // ---------------- pool: mean + max over s -> pooled (16 x 128) over w2 slot ----------------
    {
        int b = t >> 4, og = (t & 15) * 4;
        const unsigned* h2c = (const unsigned*)(s_U + 6144);
        float sm0 = 0, sm1 = 0, sm2 = 0, sm3 = 0;
        float mx0 = 0, mx1 = 0, mx2 = 0, mx3 = 0;   // h2 >= 0 after relu
        #pragma unroll
        for (int s = 0; s < 12; ++s) {
            int base = (b * 12 + s) * 33 + (og >> 1);
            unsigned ua = h2c[base], ub = h2c[base + 1];
            float v0 = bflo(ua), v1 = bfhi(ua), v2 = bflo(ub), v3 = bfhi(ub);
            sm0 += v0; sm1 += v1; sm2 += v2; sm3 += v3;
            mx0 = fmaxf(mx0, v0); mx1 = fmaxf(mx1, v1); mx2 = fmaxf(mx2, v2); mx3 = fmaxf(mx3, v3);
        }
        float* pooled = s_U;
        const float inv12 = 1.f / 12.f;
        pooled[b * 128 + og]     = sm0 * inv12;  pooled[b * 128 + og + 1] = sm1 * inv12;
        pooled[b * 128 + og + 2] = sm2 * inv12;  pooled[b * 128 + og + 3] = sm3 * inv12;
        pooled[b * 128 + 64 + og]     = mx0;     pooled[b * 128 + 64 + og + 1] = mx1;
        pooled[b * 128 + 64 + og + 2] = mx2;     pooled[b * 128 + 64 + og + 3] = mx3;
    }
    __syncthreads();

    // ---------------- fc1 (K=128, bf16 weights) ----------------
    int b  = t >> 4;
    int og = (t & 15) * 4;
    float f0, f1, f2, f3;
    {
        f0 = s_fb1[og]; f1 = s_fb1[og + 1]; f2 = s_fb1[og + 2]; f3 = s_fb1[og + 3];
        const float* pooled = s_U;
        for (int c = 0; c < 128; ++c) {
            float pv = pooled[b * 128 + c];
            unsigned u0 = s_fw1u[c * 32 + (og >> 1)];
            unsigned u1 = s_fw1u[c * 32 + (og >> 1) + 1];
            f0 += pv * bflo(u0); f1 += pv * bfhi(u0);
            f2 += pv * bflo(u1); f3 += pv * bfhi(u1);
        }
        f0 = fmaxf(f0, 0.f); f1 = fmaxf(f1, 0.f); f2 = fmaxf(f2, 0.f); f3 = fmaxf(f3, 0.f);
    }
    __syncthreads();           // fw1 reads done
    float* g1 = (float*)s_fw1u;     // 16 x 64 fp32 over fw1[0..1023]
    g1[b * 64 + og] = f0; g1[b * 64 + og + 1] = f1; g1[b * 64 + og + 2] = f2; g1[b * 64 + og + 3] = f3;
    __syncthreads();

    // ---------------- fc2 (K=64, bf16 weights) ----------------
    {
        f0 = s_fb2[og]; f1 = s_fb2[og + 1]; f2 = s_fb2[og + 2]; f3 = s_fb2[og + 3];
        for (int c = 0; c < 64; ++c) {
            float gv = g1[b * 64 + c];
            unsigned u0 = s_fw2u[c * 32 + (og >> 1)];
            unsigned u1 = s_fw2u[c * 32 + (og >> 1) + 1];
            f0 += gv * bflo(u0); f1 += gv * bfhi(u0);
            f2 += gv * bflo(u1); f3 += gv * bfhi(u1);
        }
        f0 = fmaxf(f0, 0.f); f1 = fmaxf(f1, 0.f); f2 = fmaxf(f2, 0.f); f3 = fmaxf(f3, 0.f);
    }
    __syncthreads();
    float* g2 = (float*)s_fw1u + 1024;   // over fw1[1024..2047]
    g2[b * 64 + og] = f0; g2[b * 64 + og + 1] = f1; g2[b * 64 + og + 2] = f2; g2[b * 64 + og + 3] = f3;
    __syncthreads();

    // ---------------- fc3 (K=64) + output ----------------
    if (t < 16) {
        float a = s_fb3v[0];
        for (int c = 0; c < 64; ++c) a += g2[t * 64 + c] * s_fw3[c];
        out[(size_t)(b0 + t) * LNUM + l] = a;
    }
}

extern "C" void kernel_launch(void* const* d_in, const int* in_sizes, int n_in,
                              void* d_out, int out_size, void* d_ws, size_t ws_size,
                              hipStream_t stream) {
    const float* zs  = (const float*)d_in[0];
    const float* w1  = (const float*)d_in[1];
    const float* w2  = (const float*)d_in[2];
    const float* fw1 = (const float*)d_in[3];
    const float* fb1 = (const float*)d_in[4];
    const float* fw2 = (const float*)d_in[5];
    const float* fb2 = (const float*)d_in[6];
    const float* fw3 = (const float*)d_in[7];
    const float* fb3 = (const float*)d_in[8];
    float* out = (float*)d_out;

    dim3 grid(LNUM * NBT);   // 63 * 128 = 8064 blocks, same-l blocks contiguous for L2 reuse
    dim3 block(256);
    hipLaunchKernelGGL(fused_nn, grid, block, 0, stream,
                       zs, w1, w2, fw1, fb1, fw2, fb2, fw3, fb3, out);
}

// Round 2
// 224.164 us; speedup vs baseline: 2.9257x; 2.9257x over previous
//
#include <hip/hip_runtime.h>

// TwelveSitesNN2 — MFMA version. One block = (one l, 16 b's), 256 threads (4 waves).
// Layer2 (M=192,K=96,N=64) + fc1 (M=16,K=128,N=64) + fc2 (M=16,K=64,N=64) on
// mfma_f32_16x16x32_bf16. All activations/weights bf16 in LDS, fp32 accum.
// LDS budget 73.7 KB -> 2 blocks/CU (8 waves/CU).

#define LNUM 63
#define BT 16
#define NBT 128   // 2048 / BT

typedef __attribute__((ext_vector_type(8))) short short8;
typedef __attribute__((ext_vector_type(4))) float floatx4;

__device__ __forceinline__ unsigned f2bf(float f) {
    unsigned u = __float_as_uint(f);
    return (u + 0x7fffu + ((u >> 16) & 1u)) >> 16;   // RNE
}
__device__ __forceinline__ unsigned pack2f(float a, float b) { return f2bf(a) | (f2bf(b) << 16); }
__device__ __forceinline__ float bf2f(unsigned short v) { return __uint_as_float(((unsigned)v) << 16); }
__device__ __forceinline__ int w12(int v) { return v >= 12 ? v - 12 : v; }

// LDS layout (ushort units inside U):
//   A2   @ 0      : [192][104] bf16 allc2 = [h1(32)|A(32)|B(32)] + pad   (19968)
//     after layer2: h2 [192][72] @0 ; pooled [16][136] @13824 ;
//                   pooled2 [16][72] @16000 ; g2 [16][72] @17152
//   w2T  @ 19968  : [64][104] bf16 (w2 transposed [o][c])                (6656)
//     after layer2: fw2T [64][72] bf16
//   fw1T @ 26624  : [64][136] bf16                                       (8704)
#define O_A2    0
#define O_W2T   19968
#define O_FW1T  26624
#define O_H2    0
#define O_POOL  13824
#define O_POOL2 16000
#define O_G2    17152
#define O_FW2T  19968

__global__ __launch_bounds__(256, 2) void fused_nn(
    const float* __restrict__ zs,  const float* __restrict__ w1,  const float* __restrict__ w2,
    const float* __restrict__ fw1, const float* __restrict__ fb1,
    const float* __restrict__ fw2, const float* __restrict__ fb2,
    const float* __restrict__ fw3, const float* __restrict__ fb3,
    float* __restrict__ out)
{
    __shared__ __align__(16) unsigned short U[35328];
    __shared__ __align__(16) float s_w1[192];
    __shared__ __align__(16) float s_x[BT * 24];
    __shared__ __align__(16) float s_fb1[64];
    __shared__ __align__(16) float s_fb2[64];
    __shared__ __align__(16) float s_fw3[64];
    __shared__ float s_fb3v[1];

    const int t    = threadIdx.x;
    const int lane = t & 63;
    const int wv   = t >> 6;
    const int n    = lane & 15;
    const int quad = lane >> 4;
    const int l    = blockIdx.x / NBT;
    const int b0   = (blockIdx.x % NBT) * BT;

    // ---------------- stage ----------------
    {
        // w2 -> w2T bf16 [o][c], row stride 104
        const int o = lane, g = wv;
        unsigned* w2t = (unsigned*)(U + O_W2T);
        const float* w2l = w2 + (size_t)l * 6144;
        #pragma unroll
        for (int i = 0; i < 12; ++i) {
            int cp = g + 4 * i, c = 2 * cp;
            float a = w2l[c * 64 + o], b = w2l[(c + 1) * 64 + o];
            w2t[o * 52 + cp] = pack2f(a, b);
        }
        // fw1 -> fw1T bf16 [o][c], row stride 136
        unsigned* f1t = (unsigned*)(U + O_FW1T);
        const float* f1l = fw1 + (size_t)l * 8192;
        #pragma unroll
        for (int i = 0; i < 16; ++i) {
            int cp = g + 4 * i, c = 2 * cp;
            float a = f1l[c * 64 + o], b = f1l[(c + 1) * 64 + o];
            f1t[o * 68 + cp] = pack2f(a, b);
        }
        if (t < 96) {  // zs tile: 16 b x 24 floats
            int b = t / 6, q = t - 6 * b;
            float4 f = *(const float4*)(zs + ((size_t)(b0 + b) * LNUM + l) * 24 + q * 4);
            *(float4*)(s_x + b * 24 + q * 4) = f;
        }
        if (t < 48) ((float4*)s_w1)[t] = ((const float4*)(w1 + (size_t)l * 192))[t];
        if (t >= 96  && t < 112) ((float4*)s_fw3)[t - 96]  = ((const float4*)(fw3 + (size_t)l * 64))[t - 96];
        if (t >= 112 && t < 128) ((float4*)s_fb1)[t - 112] = ((const float4*)(fb1 + (size_t)l * 64))[t - 112];
        if (t >= 128 && t < 144) ((float4*)s_fb2)[t - 128] = ((const float4*)(fb2 + (size_t)l * 64))[t - 128];
        if (t == 144) s_fb3v[0] = fb3[l];
    }
    __syncthreads();

    // ---------------- layer 1 -> A2 x-section (bf16) ----------------
    #pragma unroll
    for (int p = 0; p < 2; ++p) {
        int u = t + p * 256;
        if (u < 384) {
            int row = u >> 1;
            int b = row / 12, s = row - 12 * b;
            int ob = (u & 1) * 16;
            const float* xb = s_x + b * 24;
            int sA1 = w12(s + 1), sA2 = w12(s + 9),  sA3 = w12(s + 3), sA4 = w12(s + 11);
            int sB1 = w12(s + 2), sB2 = w12(s + 8),  sB3 = w12(s + 4), sB4 = w12(s + 10);
            float a0 = xb[s * 2],     a1 = xb[s * 2 + 1];
            float a2 = xb[sA1*2]   + xb[sA2*2]   + xb[sA3*2]   + xb[sA4*2];
            float a3 = xb[sA1*2+1] + xb[sA2*2+1] + xb[sA3*2+1] + xb[sA4*2+1];
            float a4 = xb[sB1*2]   + xb[sB2*2]   + xb[sB3*2]   + xb[sB4*2];
            float a5 = xb[sB1*2+1] + xb[sB2*2+1] + xb[sB3*2+1] + xb[sB4*2+1];
            short8 r0, r1;
            #pragma unroll
            for (int j = 0; j < 8; ++j) {
                int o = ob + j;
                float h = a0 * s_w1[o]      + a1 * s_w1[32 + o] + a2 * s_w1[64 + o]
                        + a3 * s_w1[96 + o] + a4 * s_w1[128 + o] + a5 * s_w1[160 + o];
                r0[j] = (short)f2bf(fmaxf(h, 0.f));
            }
            #pragma unroll
            for (int j = 0; j < 8; ++j) {
                int o = ob + 8 + j;
                float h = a0 * s_w1[o]      + a1 * s_w1[32 + o] + a2 * s_w1[64 + o]
                        + a3 * s_w1[96 + o] + a4 * s_w1[128 + o] + a5 * s_w1[160 + o];
                r1[j] = (short)f2bf(fmaxf(h, 0.f));
            }
            *(short8*)(U + O_A2 + row * 104 + ob)     = r0;
            *(short8*)(U + O_A2 + row * 104 + ob + 8) = r1;
        }
    }
    __syncthreads();

    // ---------------- build A2 neighbor-sum sections (bf16) ----------------
    {
        const int dtab[2][4] = {{1, 11, 3, 9}, {2, 10, 4, 8}};
        #pragma unroll
        for (int k = 0; k < 6; ++k) {
            int v = t + k * 256;                 // 1536 units: 192 rows x 2 sec x 4 ch8
            int row = v >> 3, rem = v & 7;
            int sec = rem >> 2, ch8 = (rem & 3) << 3;
            int b = row / 12, s = row - 12 * b;
            int rb = b * 12;
            short8 v0 = *(const short8*)(U + O_A2 + (rb + w12(s + dtab[sec][0])) * 104 + ch8);
            short8 v1 = *(const short8*)(U + O_A2 + (rb + w12(s + dtab[sec][1])) * 104 + ch8);
            short8 v2 = *(const short8*)(U + O_A2 + (rb + w12(s + dtab[sec][2])) * 104 + ch8);
            short8 v3 = *(const short8*)(U + O_A2 + (rb + w12(s + dtab[sec][3])) * 104 + ch8);
            short8 r;
            #pragma unroll
            for (int j = 0; j < 8; ++j) {
                float f = bf2f((unsigned short)v0[j]) + bf2f((unsigned short)v1[j])
                        + bf2f((unsigned short)v2[j]) + bf2f((unsigned short)v3[j]);
                r[j] = (short)f2bf(f);
            }
            *(short8*)(U + O_A2 + row * 104 + 32 + sec * 32 + ch8) = r;
        }
    }
    __syncthreads();

    // ---------------- layer 2: MFMA  (M=192, K=96, N=64) ----------------
    floatx4 acc[3][4];
    #pragma unroll
    for (int mi = 0; mi < 3; ++mi)
        #pragma unroll
        for (int nt = 0; nt < 4; ++nt) acc[mi][nt] = (floatx4){0.f, 0.f, 0.f, 0.f};
    {
        short8 af[3][3], bf[4][3];
        #pragma unroll
        for (int mi = 0; mi < 3; ++mi) {
            int row = (3 * wv + mi) * 16 + n;
            #pragma unroll
            for (int ks = 0; ks < 3; ++ks)
                af[mi][ks] = *(const short8*)(U + O_A2 + row * 104 + ks * 32 + quad * 8);
        }
        #pragma unroll
        for (int nt = 0; nt < 4; ++nt) {
            int o = nt * 16 + n;
            #pragma unroll
            for (int ks = 0; ks < 3; ++ks)
                bf[nt][ks] = *(const short8*)(U + O_W2T + o * 104 + ks * 32 + quad * 8);
        }
        #pragma unroll
        for (int ks = 0; ks < 3; ++ks)
            #pragma unroll
            for (int mi = 0; mi < 3; ++mi)
                #pragma unroll
                for (int nt = 0; nt < 4; ++nt)
                    acc[mi][nt] = __builtin_amdgcn_mfma_f32_16x16x32_bf16(af[mi][ks], bf[nt][ks], acc[mi][nt], 0, 0, 0);
    }
    __syncthreads();   // A2 / w2T reads complete -> safe to overlay

    // ---------------- h2 -> LDS (bf16, [192][72]) + late-stage fw2T ----------------
    {
        #pragma unroll
        for (int mi = 0; mi < 3; ++mi) {
            int rbase = (3 * wv + mi) * 16 + quad * 4;
            #pragma unroll
            for (int nt = 0; nt < 4; ++nt) {
                int o = nt * 16 + n;
                #pragma unroll
                for (int i = 0; i < 4; ++i)
                    U[O_H2 + (rbase + i) * 72 + o] = (unsigned short)f2bf(fmaxf(acc[mi][nt][i], 0.f));
            }
        }
        // fw2 -> fw2T bf16 [o][c], row stride 72 (overlays w2T region)
        const int o = lane, g = wv;
        unsigned* f2t = (unsigned*)(U + O_FW2T);
        const float* f2l = fw2 + (size_t)l * 4096;
        #pragma unroll
        for (int i = 0; i < 8; ++i) {
            int cp = g + 4 * i, c = 2 * cp;
            float a = f2l[c * 64 + o], b = f2l[(c + 1) * 64 + o];
            f2t[o * 36 + cp] = pack2f(a, b);
        }
    }
    __syncthreads();

    // ---------------- pool: mean + max over s -> pooled bf16 [16][136] ----------------
    {
        int b = t >> 4, oq = (t & 15) * 4;
        float sm0 = 0, sm1 = 0, sm2 = 0, sm3 = 0;
        float mx0 = 0, mx1 = 0, mx2 = 0, mx3 = 0;
        #pragma unroll
        for (int s = 0; s < 12; ++s) {
            uint2 u2 = *(const uint2*)(U + O_H2 + (b * 12 + s) * 72 + oq);
            float v0 = bf2f((unsigned short)(u2.x & 0xffff)), v1 = bf2f((unsigned short)(u2.x >> 16));
            float v2 = bf2f((unsigned short)(u2.y & 0xffff)), v3 = bf2f((unsigned short)(u2.y >> 16));
            sm0 += v0; sm1 += v1; sm2 += v2; sm3 += v3;
            mx0 = fmaxf(mx0, v0); mx1 = fmaxf(mx1, v1); mx2 = fmaxf(mx2, v2); mx3 = fmaxf(mx3, v3);
        }
        const float inv12 = 1.f / 12.f;
        uint2 mo, xo;
        mo.x = pack2f(sm0 * inv12, sm1 * inv12); mo.y = pack2f(sm2 * inv12, sm3 * inv12);
        xo.x = pack2f(mx0, mx1);                 xo.y = pack2f(mx2, mx3);
        *(uint2*)(U + O_POOL + b * 136 + oq)      = mo;
        *(uint2*)(U + O_POOL + b * 136 + 64 + oq) = xo;
    }
    __syncthreads();

    // ---------------- fc1: MFMA (M=16, K=128, N=64; wave w does nt=w) ----------------
    {
        int o = wv * 16 + n;
        float bias = s_fb1[o];
        floatx4 a1 = (floatx4){bias, bias, bias, bias};
        #pragma unroll
        for (int ks = 0; ks < 4; ++ks) {
            short8 av = *(const short8*)(U + O_POOL + n * 136 + ks * 32 + quad * 8);
            short8 bv = *(const short8*)(U + O_FW1T + o * 136 + ks * 32 + quad * 8);
            a1 = __builtin_amdgcn_mfma_f32_16x16x32_bf16(av, bv, a1, 0, 0, 0);
        }
        __syncthreads();
        #pragma unroll
        for (int i = 0; i < 4; ++i)
            U[O_POOL2 + (quad * 4 + i) * 72 + o] = (unsigned short)f2bf(fmaxf(a1[i], 0.f));
    }
    __syncthreads();

    // ---------------- fc2: MFMA (M=16, K=64, N=64) ----------------
    {
        int o = wv * 16 + n;
        float bias = s_fb2[o];
        floatx4 a2 = (floatx4){bias, bias, bias, bias};
        #pragma unroll
        for (int ks = 0; ks < 2; ++ks) {
            short8 av = *(const short8*)(U + O_POOL2 + n * 72 + ks * 32 + quad * 8);
            short8 bv = *(const short8*)(U + O_FW2T + o * 72 + ks * 32 + quad * 8);
            a2 = __builtin_amdgcn_mfma_f32_16x16x32_bf16(av, bv, a2, 0, 0, 0);
        }
        __syncthreads();
        #pragma unroll
        for (int i = 0; i < 4; ++i)
            U[O_G2 + (quad * 4 + i) * 72 + o] = (unsigned short)f2bf(fmaxf(a2[i], 0.f));
    }
    __syncthreads();

    // ---------------- fc3 (K=64) + output ----------------
    if (t < 16) {
        float a = s_fb3v[0];
        #pragma unroll
        for (int c4 = 0; c4 < 16; ++c4) {
            uint2 u2 = *(const uint2*)(U + O_G2 + t * 72 + c4 * 4);
            a += bf2f((unsigned short)(u2.x & 0xffff)) * s_fw3[c4 * 4]
               + bf2f((unsigned short)(u2.x >> 16))    * s_fw3[c4 * 4 + 1]
               + bf2f((unsigned short)(u2.y & 0xffff)) * s_fw3[c4 * 4 + 2]
               + bf2f((unsigned short)(u2.y >> 16))    * s_fw3[c4 * 4 + 3];
        }
        out[(size_t)(b0 + t) * LNUM + l] = a;
    }
}

extern "C" void kernel_launch(void* const* d_in, const int* in_sizes, int n_in,
                              void* d_out, int out_size, void* d_ws, size_t ws_size,
                              hipStream_t stream) {
    const float* zs  = (const float*)d_in[0];
    const float* w1  = (const float*)d_in[1];
    const float* w2  = (const float*)d_in[2];
    const float* fw1 = (const float*)d_in[3];
    const float* fb1 = (const float*)d_in[4];
    const float* fw2 = (const float*)d_in[5];
    const float* fb2 = (const float*)d_in[6];
    const float* fw3 = (const float*)d_in[7];
    const float* fb3 = (const float*)d_in[8];
    float* out = (float*)d_out;

    dim3 grid(LNUM * NBT);   // 8064 blocks; same-l blocks contiguous for L2 weight reuse
    dim3 block(256);
    hipLaunchKernelGGL(fused_nn, grid, block, 0, stream,
                       zs, w1, w2, fw1, fb1, fw2, fb2, fw3, fb3, out);
}

// Round 3
// 202.679 us; speedup vs baseline: 3.2358x; 1.1060x over previous
//
#include <hip/hip_runtime.h>

// TwelveSitesNN2 R3: prep kernel pre-transposes weights to bf16 in d_ws;
// main kernel fuses layer1+neighbor-sums thread-locally, layer2/fc1/fc2 on MFMA.
// One main block = (one l, 16 b's), 256 threads (4 waves). LDS ~74 KB -> 2 blocks/CU.

#define LNUM 63
#define BT 16
#define NBT 128   // 2048 / BT
#define WSL 19968 // ushorts per l in ws: [w2T 64x104][fw1T 64x136][fw2T 64x72]

typedef __attribute__((ext_vector_type(8))) short short8;
typedef __attribute__((ext_vector_type(4))) float floatx4;

// bf16 round-to-nearest (ties away) pack of two floats into one dword: 3 VALU ops.
__device__ __forceinline__ unsigned cvtpk(float a, float b) {
    return __builtin_amdgcn_perm(__float_as_uint(b) + 0x8000u,
                                 __float_as_uint(a) + 0x8000u, 0x07060302u);
}
__device__ __forceinline__ float bf2f(unsigned short v) { return __uint_as_float(((unsigned)v) << 16); }
__device__ __forceinline__ int w12(int v) { return v >= 12 ? v - 12 : v; }

// LDS layout (ushort idx):
//   A2   @ 0     : [192][104] allc2 bf16                              (19968 ush)
//     post-GEMM  : h2T [64][202] @0 ; pooled [16][136] @13056 ;
//                  pooled2 [16][72] @15232 ; g2 [16][72] @16384
//   w2T  @ 19968 : [64][104] bf16 -> later fw2T [64][72]
//   fw1T @ 26624 : [64][136] bf16
#define O_A2    0
#define O_W2T   19968
#define O_FW1T  26624
#define O_H2T   0
#define O_POOL  13056
#define O_POOL2 15232
#define O_G2    16384
#define O_FW2T  19968

__global__ void prep(const float* __restrict__ w2, const float* __restrict__ fw1,
                     const float* __restrict__ fw2, unsigned short* __restrict__ ws) {
    const int l = blockIdx.x, t = threadIdx.x;
    const int o = t & 63, g = t >> 6;
    unsigned* w2t = (unsigned*)(ws + (size_t)l * WSL);
    const float* w2l = w2 + (size_t)l * 6144;
    #pragma unroll
    for (int i = 0; i < 12; ++i) {
        int cp = g + 4 * i, c = 2 * cp;
        w2t[o * 52 + cp] = cvtpk(w2l[c * 64 + o], w2l[(c + 1) * 64 + o]);
    }
    unsigned* f1t = (unsigned*)(ws + (size_t)l * WSL + 6656);
    const float* f1l = fw1 + (size_t)l * 8192;
    #pragma unroll
    for (int i = 0; i < 16; ++i) {
        int cp = g + 4 * i, c = 2 * cp;
        f1t[o * 68 + cp] = cvtpk(f1l[c * 64 + o], f1l[(c + 1) * 64 + o]);
    }
    unsigned* f2t = (unsigned*)(ws + (size_t)l * WSL + 15360);
    const float* f2l = fw2 + (size_t)l * 4096;
    #pragma unroll
    for (int i = 0; i < 8; ++i) {
        int cp = g + 4 * i, c = 2 * cp;
        f2t[o * 36 + cp] = cvtpk(f2l[c * 64 + o], f2l[(c + 1) * 64 + o]);
    }
}

__global__ __launch_bounds__(256, 2) void fused_nn(
    const float* __restrict__ zs,  const float* __restrict__ w1,  const float* __restrict__ w2,
    const float* __restrict__ fw1, const float* __restrict__ fb1,
    const float* __restrict__ fw2, const float* __restrict__ fb2,
    const float* __restrict__ fw3, const float* __restrict__ fb3,
    const unsigned short* __restrict__ ws, const int use_ws,
    float* __restrict__ out)
{
    __shared__ __align__(16) unsigned short U[35328];
    __shared__ __align__(16) float s_w1[192];
    __shared__ __align__(16) float s_x[BT * 24];
    __shared__ __align__(16) float s_fb1[64];
    __shared__ __align__(16) float s_fb2[64];
    __shared__ __align__(16) float s_fw3[64];
    __shared__ float s_fb3v[1];

    const int t    = threadIdx.x;
    const int lane = t & 63;
    const int wv   = t >> 6;
    const int n    = lane & 15;
    const int quad = lane >> 4;
    const int l    = blockIdx.x / NBT;
    const int b0   = (blockIdx.x % NBT) * BT;

    // ---------------- stage ----------------
    if (use_ws) {
        const float4* src = (const float4*)(ws + (size_t)l * WSL);
        float4* dst = (float4*)(U + O_W2T);   // w2T + fw1T contiguous: 1920 float4
        #pragma unroll
        for (int k = 0; k < 8; ++k) {
            int i = t + 256 * k;
            if (i < 1920) dst[i] = src[i];
        }
    } else {
        const int o = lane, g = wv;
        unsigned* w2t = (unsigned*)(U + O_W2T);
        const float* w2l = w2 + (size_t)l * 6144;
        #pragma unroll
        for (int i = 0; i < 12; ++i) {
            int cp = g + 4 * i, c = 2 * cp;
            w2t[o * 52 + cp] = cvtpk(w2l[c * 64 + o], w2l[(c + 1) * 64 + o]);
        }
        unsigned* f1t = (unsigned*)(U + O_FW1T);
        const float* f1l = fw1 + (size_t)l * 8192;
        #pragma unroll
        for (int i = 0; i < 16; ++i) {
            int cp = g + 4 * i, c = 2 * cp;
            f1t[o * 68 + cp] = cvtpk(f1l[c * 64 + o], f1l[(c + 1) * 64 + o]);
        }
    }
    {
        if (t < 96) {  // zs tile: 16 b x 24 floats
            int b = t / 6, q = t - 6 * b;
            float4 f = *(const float4*)(zs + ((size_t)(b0 + b) * LNUM + l) * 24 + q * 4);
            *(float4*)(s_x + b * 24 + q * 4) = f;
        }
        if (t < 48) ((float4*)s_w1)[t] = ((const float4*)(w1 + (size_t)l * 192))[t];
        if (t >= 96  && t < 112) ((float4*)s_fw3)[t - 96]  = ((const float4*)(fw3 + (size_t)l * 64))[t - 96];
        if (t >= 112 && t < 128) ((float4*)s_fb1)[t - 112] = ((const float4*)(fb1 + (size_t)l * 64))[t - 112];
        if (t >= 128 && t < 144) ((float4*)s_fb2)[t - 128] = ((const float4*)(fb2 + (size_t)l * 64))[t - 128];
        if (t == 144) s_fb3v[0] = fb3[l];
    }
    __syncthreads();

    // ---------------- layer 1 + neighbor-sums, thread-local over sites ----------------
    // thread = (b, channel pair c0=2*(t&15)); h1[12 sites] in regs, A/B sums in fp32.
    {
        const int b = t >> 4, c0 = (t & 15) * 2;
        const float* xb = s_x + b * 24;
        float2 xv[12];
        #pragma unroll
        for (int s = 0; s < 12; ++s) xv[s] = *(const float2*)(xb + 2 * s);
        const float2 wv0 = *(const float2*)(s_w1 + c0);
        const float2 wv1 = *(const float2*)(s_w1 + 32 + c0);
        const float2 wv2 = *(const float2*)(s_w1 + 64 + c0);
        const float2 wv3 = *(const float2*)(s_w1 + 96 + c0);
        const float2 wv4 = *(const float2*)(s_w1 + 128 + c0);
        const float2 wv5 = *(const float2*)(s_w1 + 160 + c0);
        float2 h1v[12];
        #pragma unroll
        for (int s = 0; s < 12; ++s) {
            float xAx = xv[w12(s+1)].x + xv[w12(s+11)].x + xv[w12(s+3)].x + xv[w12(s+9)].x;
            float xAy = xv[w12(s+1)].y + xv[w12(s+11)].y + xv[w12(s+3)].y + xv[w12(s+9)].y;
            float xBx = xv[w12(s+2)].x + xv[w12(s+10)].x + xv[w12(s+4)].x + xv[w12(s+8)].x;
            float xBy = xv[w12(s+2)].y + xv[w12(s+10)].y + xv[w12(s+4)].y + xv[w12(s+8)].y;
            float hx = xv[s].x*wv0.x + xv[s].y*wv1.x + xAx*wv2.x + xAy*wv3.x + xBx*wv4.x + xBy*wv5.x;
            float hy = xv[s].x*wv0.y + xv[s].y*wv1.y + xAx*wv2.y + xAy*wv3.y + xBx*wv4.y + xBy*wv5.y;
            h1v[s].x = fmaxf(hx, 0.f);
            h1v[s].y = fmaxf(hy, 0.f);
        }
        #pragma unroll
        for (int s = 0; s < 12; ++s) {
            float hAx = h1v[w12(s+1)].x + h1v[w12(s+11)].x + h1v[w12(s+3)].x + h1v[w12(s+9)].x;
            float hAy = h1v[w12(s+1)].y + h1v[w12(s+11)].y + h1v[w12(s+3)].y + h1v[w12(s+9)].y;
            float hBx = h1v[w12(s+2)].x + h1v[w12(s+10)].x + h1v[w12(s+4)].x + h1v[w12(s+8)].x;
            float hBy = h1v[w12(s+2)].y + h1v[w12(s+10)].y + h1v[w12(s+4)].y + h1v[w12(s+8)].y;
            unsigned* dst = (unsigned*)(U + O_A2 + (b * 12 + s) * 104 + c0);
            dst[0]  = cvtpk(h1v[s].x, h1v[s].y);
            dst[16] = cvtpk(hAx, hAy);
            dst[32] = cvtpk(hBx, hBy);
        }
    }
    __syncthreads();

    // ---------------- layer 2: MFMA (M=192, K=96, N=64) ----------------
    floatx4 acc[3][4];
    #pragma unroll
    for (int mi = 0; mi < 3; ++mi)
        #pragma unroll
        for (int nt = 0; nt < 4; ++nt) acc[mi][nt] = (floatx4){0.f, 0.f, 0.f, 0.f};
    {
        short8 af[3][3], bfr[4][3];
        #pragma unroll
        for (int mi = 0; mi < 3; ++mi) {
            int row = (3 * wv + mi) * 16 + n;
            #pragma unroll
            for (int ks = 0; ks < 3; ++ks)
                af[mi][ks] = *(const short8*)(U + O_A2 + row * 104 + ks * 32 + quad * 8);
        }
        #pragma unroll
        for (int nt = 0; nt < 4; ++nt) {
            int o = nt * 16 + n;
            #pragma unroll
            for (int ks = 0; ks < 3; ++ks)
                bfr[nt][ks] = *(const short8*)(U + O_W2T + o * 104 + ks * 32 + quad * 8);
        }
        #pragma unroll
        for (int ks = 0; ks < 3; ++ks)
            #pragma unroll
            for (int mi = 0; mi < 3; ++mi)
                #pragma unroll
                for (int nt = 0; nt < 4; ++nt)
                    acc[mi][nt] = __builtin_amdgcn_mfma_f32_16x16x32_bf16(af[mi][ks], bfr[nt][ks], acc[mi][nt], 0, 0, 0);
    }
    __syncthreads();   // A2 / w2T reads complete -> safe to overlay

    // ---------------- h2 -> LDS transposed bf16 [o][row], stride 202 + stage fw2T ----------------
    {
        #pragma unroll
        for (int mi = 0; mi < 3; ++mi) {
            int r0 = (3 * wv + mi) * 16 + quad * 4;
            #pragma unroll
            for (int nt = 0; nt < 4; ++nt) {
                int o = nt * 16 + n;
                unsigned* dst = (unsigned*)(U + O_H2T + o * 202 + r0);
                dst[0] = cvtpk(fmaxf(acc[mi][nt][0], 0.f), fmaxf(acc[mi][nt][1], 0.f));
                dst[1] = cvtpk(fmaxf(acc[mi][nt][2], 0.f), fmaxf(acc[mi][nt][3], 0.f));
            }
        }
        if (use_ws) {
            const float4* src = (const float4*)(ws + (size_t)l * WSL) + 1920;
            float4* dst = (float4*)(U + O_FW2T);
            #pragma unroll
            for (int k = 0; k < 3; ++k) {
                int i = t + 256 * k;
                if (i < 576) dst[i] = src[i];
            }
        } else {
            const int o = lane, g = wv;
            unsigned* f2t = (unsigned*)(U + O_FW2T);
            const float* f2l = fw2 + (size_t)l * 4096;
            #pragma unroll
            for (int i = 0; i < 8; ++i) {
                int cp = g + 4 * i, c = 2 * cp;
                f2t[o * 36 + cp] = cvtpk(f2l[c * 64 + o], f2l[(c + 1) * 64 + o]);
            }
        }
    }
    __syncthreads();

    // ---------------- pool: mean + max over s -> pooled bf16 [16][136] ----------------
    {
        const int o = lane, bg = wv;
        #pragma unroll
        for (int bb = 0; bb < 4; ++bb) {
            int b = bg * 4 + bb;
            const unsigned* src = (const unsigned*)(U + O_H2T + o * 202 + b * 12);
            float sm = 0.f, mx = 0.f;
            #pragma unroll
            for (int j = 0; j < 6; ++j) {
                unsigned u = src[j];
                float v0 = __uint_as_float(u << 16);
                float v1 = __uint_as_float(u & 0xffff0000u);
                sm += v0 + v1;
                mx = fmaxf(mx, fmaxf(v0, v1));
            }
            unsigned pk = cvtpk(sm * (1.f / 12.f), mx);
            U[O_POOL + b * 136 + o]      = (unsigned short)(pk & 0xffffu);
            U[O_POOL + b * 136 + 64 + o] = (unsigned short)(pk >> 16);
        }
    }
    __syncthreads();

    // ---------------- fc1: MFMA (M=16, K=128, N=64) ----------------
    {
        int o = wv * 16 + n;
        float bias = s_fb1[o];
        floatx4 a1 = (floatx4){bias, bias, bias, bias};
        #pragma unroll
        for (int ks = 0; ks < 4; ++ks) {
            short8 av = *(const short8*)(U + O_POOL + n * 136 + ks * 32 + quad * 8);
            short8 bv = *(const short8*)(U + O_FW1T + o * 136 + ks * 32 + quad * 8);
            a1 = __builtin_amdgcn_mfma_f32_16x16x32_bf16(av, bv, a1, 0, 0, 0);
        }
        __syncthreads();
        #pragma unroll
        for (int i = 0; i < 2; ++i) {
            unsigned pk = cvtpk(fmaxf(a1[2*i], 0.f), fmaxf(a1[2*i+1], 0.f));
            U[O_POOL2 + (quad * 4 + 2*i)     * 72 + o] = (unsigned short)(pk & 0xffffu);
            U[O_POOL2 + (quad * 4 + 2*i + 1) * 72 + o] = (unsigned short)(pk >> 16);
        }
    }
    __syncthreads();

    // ---------------- fc2: MFMA (M=16, K=64, N=64) ----------------
    {
        int o = wv * 16 + n;
        float bias = s_fb2[o];
        floatx4 a2 = (floatx4){bias, bias, bias, bias};
        #pragma unroll
        for (int ks = 0; ks < 2; ++ks) {
            short8 av = *(const short8*)(U + O_POOL2 + n * 72 + ks * 32 + quad * 8);
            short8 bv = *(const short8*)(U + O_FW2T + o * 72 + ks * 32 + quad * 8);
            a2 = __builtin_amdgcn_mfma_f32_16x16x32_bf16(av, bv, a2, 0, 0, 0);
        }
        __syncthreads();
        #pragma unroll
        for (int i = 0; i < 2; ++i) {
            unsigned pk = cvtpk(fmaxf(a2[2*i], 0.f), fmaxf(a2[2*i+1], 0.f));
            U[O_G2 + (quad * 4 + 2*i)     * 72 + o] = (unsigned short)(pk & 0xffffu);
            U[O_G2 + (quad * 4 + 2*i + 1) * 72 + o] = (unsigned short)(pk >> 16);
        }
    }
    __syncthreads();

    // ---------------- fc3 (K=64) + output ----------------
    if (t < 16) {
        float a = s_fb3v[0];
        #pragma unroll
        for (int c4 = 0; c4 < 16; ++c4) {
            uint2 u2 = *(const uint2*)(U + O_G2 + t * 72 + c4 * 4);
            a += bf2f((unsigned short)(u2.x & 0xffff)) * s_fw3[c4 * 4]
               + bf2f((unsigned short)(u2.x >> 16))    * s_fw3[c4 * 4 + 1]
               + bf2f((unsigned short)(u2.y & 0xffff)) * s_fw3[c4 * 4 + 2]
               + bf2f((unsigned short)(u2.y >> 16))    * s_fw3[c4 * 4 + 3];
        }
        out[(size_t)(b0 + t) * LNUM + l] = a;
    }
}

extern "C" void kernel_launch(void* const* d_in, const int* in_sizes, int n_in,
                              void* d_out, int out_size, void* d_ws, size_t ws_size,
                              hipStream_t stream) {
    const float* zs  = (const float*)d_in[0];
    const float* w1  = (const float*)d_in[1];
    const float* w2  = (const float*)d_in[2];
    const float* fw1 = (const float*)d_in[3];
    const float* fb1 = (const float*)d_in[4];
    const float* fw2 = (const float*)d_in[5];
    const float* fb2 = (const float*)d_in[6];
    const float* fw3 = (const float*)d_in[7];
    const float* fb3 = (const float*)d_in[8];
    float* out = (float*)d_out;
    unsigned short* ws = (unsigned short*)d_ws;

    const int use_ws = (ws_size >= (size_t)LNUM * WSL * 2) ? 1 : 0;
    if (use_ws)
        hipLaunchKernelGGL(prep, dim3(LNUM), dim3(256), 0, stream, w2, fw1, fw2, ws);
    hipLaunchKernelGGL(fused_nn, dim3(LNUM * NBT), dim3(256), 0, stream,
                       zs, w1, w2, fw1, fb1, fw2, fb2, fw3, fb3, ws, use_ws, out);
}

// Round 6
// 138.412 us; speedup vs baseline: 4.7383x; 1.4643x over previous
//
#include <hip/hip_runtime.h>

// TwelveSitesNN2 R4c: all-f16 datapath, weights as MFMA B-fragments straight from
// prepped ws (no LDS weight staging) -> LDS ~39.4KB -> 4 blocks/CU (16 waves).
// Layer1 + neighbor sums thread-local (factored + packed-f16), layer2/fc1/fc2 on
// mfma_f32_16x16x32_f16. (fix: cvt_pkrtz returns __fp16x2 — bit_cast that.)

#define LNUM 63
#define BT 16
#define NBT 128   // 2048 / BT
#define WSL 19968 // ushorts per l in ws: [w2T 64x104][fw1T 64x136][fw2T 64x72] (f16)

typedef __attribute__((ext_vector_type(8))) _Float16 half8;
typedef __attribute__((ext_vector_type(2))) _Float16 half2v;
typedef __attribute__((ext_vector_type(4))) float floatx4;
typedef __attribute__((ext_vector_type(4))) unsigned uint4v;

static __device__ __forceinline__ unsigned cvtpk(float a, float b) {
    return __builtin_bit_cast(unsigned, __builtin_amdgcn_cvt_pkrtz(a, b));  // 1 VALU op
}
static __device__ __forceinline__ half2v u2h(unsigned u) { return __builtin_bit_cast(half2v, u); }
static __device__ __forceinline__ unsigned h2u(half2v h) { return __builtin_bit_cast(unsigned, h); }
static __device__ __forceinline__ half2v hmax2(half2v a, half2v b) {
    half2v r;
    r[0] = a[0] > b[0] ? a[0] : b[0];
    r[1] = a[1] > b[1] ? a[1] : b[1];
    return r;
}
static __device__ __forceinline__ float hlo16(unsigned short s) {
    return (float)__builtin_bit_cast(_Float16, s);
}
static __device__ __forceinline__ int w12(int v) { return v >= 12 ? v - 12 : v; }
static __device__ __forceinline__ float2 add2(float2 a, float2 b) { return make_float2(a.x + b.x, a.y + b.y); }

// LDS layout (ushort idx inside U, total 18432 ush = 36864 B):
//   phase1: A2 [192][96] f16 allc2, XOR-swizzled 16B granules (granule ^= row&3)
//   phase2 overlays: h2T [64][202] @0 ; pooled [16][136] @13056 ;
//                    pooled2 [16][72] @15232 ; g2 [16][72] @16384
#define O_POOL  13056
#define O_POOL2 15232
#define O_G2    16384

__global__ void prep(const float* __restrict__ w2, const float* __restrict__ fw1,
                     const float* __restrict__ fw2, unsigned short* __restrict__ ws) {
    const int l = blockIdx.x, t = threadIdx.x;
    const int o = t & 63, g = t >> 6;
    unsigned* w2t = (unsigned*)(ws + (size_t)l * WSL);
    const float* w2l = w2 + (size_t)l * 6144;
    #pragma unroll
    for (int i = 0; i < 12; ++i) {
        int cp = g + 4 * i, c = 2 * cp;
        w2t[o * 52 + cp] = cvtpk(w2l[c * 64 + o], w2l[(c + 1) * 64 + o]);
    }
    unsigned* f1t = (unsigned*)(ws + (size_t)l * WSL + 6656);
    const float* f1l = fw1 + (size_t)l * 8192;
    #pragma unroll
    for (int i = 0; i < 16; ++i) {
        int cp = g + 4 * i, c = 2 * cp;
        f1t[o * 68 + cp] = cvtpk(f1l[c * 64 + o], f1l[(c + 1) * 64 + o]);
    }
    unsigned* f2t = (unsigned*)(ws + (size_t)l * WSL + 15360);
    const float* f2l = fw2 + (size_t)l * 4096;
    #pragma unroll
    for (int i = 0; i < 8; ++i) {
        int cp = g + 4 * i, c = 2 * cp;
        f2t[o * 36 + cp] = cvtpk(f2l[c * 64 + o], f2l[(c + 1) * 64 + o]);
    }
}

__global__ __launch_bounds__(256, 4) void fused_nn(
    const float* __restrict__ zs,  const float* __restrict__ w1,
    const float* __restrict__ fb1, const float* __restrict__ fb2,
    const float* __restrict__ fw3, const float* __restrict__ fb3,
    const unsigned short* __restrict__ ws,
    float* __restrict__ out)
{
    __shared__ __align__(16) unsigned short U[18432];
    __shared__ __align__(16) float s_w1[192];
    __shared__ __align__(16) float s_x[BT * 24];
    __shared__ __align__(16) float s_fw3[64];

    const int t    = threadIdx.x;
    const int lane = t & 63;
    const int wv   = t >> 6;
    const int n    = lane & 15;
    const int quad = lane >> 4;
    const int l    = blockIdx.x / NBT;
    const int b0   = (blockIdx.x % NBT) * BT;

    // ---------------- stage (x + w1 + fw3 only) ----------------
    if (t < 96) {  // zs tile: 16 b x 24 floats
        int b = t / 6, q = t - 6 * b;
        float4 f = *(const float4*)(zs + ((size_t)(b0 + b) * LNUM + l) * 24 + q * 4);
        *(float4*)(s_x + b * 24 + q * 4) = f;
    }
    if (t < 48) ((float4*)s_w1)[t] = ((const float4*)(w1 + (size_t)l * 192))[t];
    if (t >= 96 && t < 112) ((float4*)s_fw3)[t - 96] = ((const float4*)(fw3 + (size_t)l * 64))[t - 96];
    __syncthreads();

    // ---------------- layer 1 + neighbor sums, thread-local ----------------
    // thread = (b = t>>4, channel pair cpair = t&15). A=(C+C^-1)(C^2+C^-2), B=(C+C^-1)(C^3+C^-3).
    {
        const int b = t >> 4, cpair = t & 15, c0 = cpair * 2;
        const float* xb = s_x + b * 24;
        float2 xv[12], xr[12], xA[12], xB[12];
        #pragma unroll
        for (int s = 0; s < 12; ++s) xv[s] = *(const float2*)(xb + 2 * s);
        #pragma unroll
        for (int s = 0; s < 12; ++s) xr[s] = add2(xv[w12(s + 1)], xv[w12(s + 11)]);
        #pragma unroll
        for (int s = 0; s < 12; ++s) {
            xA[s] = add2(xr[w12(s + 2)], xr[w12(s + 10)]);
            xB[s] = add2(xr[w12(s + 3)], xr[w12(s + 9)]);
        }
        const float2 w0 = *(const float2*)(s_w1 + c0);
        const float2 w1v = *(const float2*)(s_w1 + 32 + c0);
        const float2 w2v = *(const float2*)(s_w1 + 64 + c0);
        const float2 w3v = *(const float2*)(s_w1 + 96 + c0);
        const float2 w4v = *(const float2*)(s_w1 + 128 + c0);
        const float2 w5v = *(const float2*)(s_w1 + 160 + c0);
        unsigned hp[12];
        #pragma unroll
        for (int s = 0; s < 12; ++s) {
            float hx = xv[s].x*w0.x + xv[s].y*w1v.x + xA[s].x*w2v.x + xA[s].y*w3v.x
                     + xB[s].x*w4v.x + xB[s].y*w5v.x;
            float hy = xv[s].x*w0.y + xv[s].y*w1v.y + xA[s].x*w2v.y + xA[s].y*w3v.y
                     + xB[s].x*w4v.y + xB[s].y*w5v.y;
            hp[s] = cvtpk(fmaxf(hx, 0.f), fmaxf(hy, 0.f));
        }
        half2v hh[12], hr[12];
        #pragma unroll
        for (int s = 0; s < 12; ++s) hh[s] = u2h(hp[s]);
        #pragma unroll
        for (int s = 0; s < 12; ++s) hr[s] = hh[w12(s + 1)] + hh[w12(s + 11)];
        unsigned* dwU = (unsigned*)U;
        const int g = cpair >> 2, jj = cpair & 3;
        #pragma unroll
        for (int s = 0; s < 12; ++s) {
            half2v hA = hr[w12(s + 2)] + hr[w12(s + 10)];
            half2v hB = hr[w12(s + 3)] + hr[w12(s + 9)];
            const int row = b * 12 + s;
            const int base = row * 48 + ((g ^ (s & 3)) << 2) + jj;  // swizzled granule
            dwU[base]      = hp[s];
            dwU[base + 16] = h2u(hA);
            dwU[base + 32] = h2u(hB);
        }
    }
    __syncthreads();

    // ---------------- layer 2: MFMA f16 (M=192, K=96, N=64), B-frags from ws ----------------
    floatx4 acc[3][4];
    #pragma unroll
    for (int mi = 0; mi < 3; ++mi)
        #pragma unroll
        for (int nt = 0; nt < 4; ++nt) acc[mi][nt] = (floatx4){0.f, 0.f, 0.f, 0.f};
    {
        half8 af[3][3];
        const int sw = (quad ^ (n & 3)) * 8;
        #pragma unroll
        for (int mi = 0; mi < 3; ++mi) {
            const int row = (3 * wv + mi) * 16 + n;
            #pragma unroll
            for (int ks = 0; ks < 3; ++ks)
                af[mi][ks] = *(const half8*)(U + row * 96 + ks * 32 + sw);
        }
        const uint4v* w2q = (const uint4v*)(ws + (size_t)l * WSL);
        #pragma unroll
        for (int ks = 0; ks < 3; ++ks) {
            uint4v bw[4];
            #pragma unroll
            for (int nt = 0; nt < 4; ++nt)
                bw[nt] = w2q[(nt * 16 + n) * 13 + ks * 4 + quad];
            #pragma unroll
            for (int mi = 0; mi < 3; ++mi)
                #pragma unroll
                for (int nt = 0; nt < 4; ++nt)
                    acc[mi][nt] = __builtin_amdgcn_mfma_f32_16x16x32_f16(
                        af[mi][ks], __builtin_bit_cast(half8, bw[nt]), acc[mi][nt], 0, 0, 0);
        }
    }
    __syncthreads();   // all A2 reads done -> safe to overlay

    // ---------------- h2 -> LDS transposed f16 [o][row], stride 202 ----------------
    #pragma unroll
    for (int mi = 0; mi < 3; ++mi) {
        const int r0 = (3 * wv + mi) * 16 + quad * 4;
        #pragma unroll
        for (int nt = 0; nt < 4; ++nt) {
            const int o = nt * 16 + n;
            unsigned* dst = (unsigned*)U + o * 101 + (r0 >> 1);
            dst[0] = cvtpk(fmaxf(acc[mi][nt][0], 0.f), fmaxf(acc[mi][nt][1], 0.f));
            dst[1] = cvtpk(fmaxf(acc[mi][nt][2], 0.f), fmaxf(acc[mi][nt][3], 0.f));
        }
    }
    __syncthreads();

    // ---------------- pool: mean+max over s (packed-f16 math) ----------------
    {
        const int o = lane;
        #pragma unroll
        for (int bb = 0; bb < 4; ++bb) {
            const int b = wv * 4 + bb;
            const half2v* src = (const half2v*)(U + o * 202 + b * 12);
            half2v v0 = src[0];
            half2v sm = v0, mx = v0;
            #pragma unroll
            for (int j = 1; j < 6; ++j) {
                half2v v = src[j];
                sm = sm + v;
                mx = hmax2(mx, v);
            }
            float s = (float)sm[0] + (float)sm[1];
            float m = fmaxf((float)mx[0], (float)mx[1]);
            unsigned pk = cvtpk(s * (1.f / 12.f), m);
            U[O_POOL + b * 136 + o]      = (unsigned short)(pk & 0xffffu);
            U[O_POOL + b * 136 + 64 + o] = (unsigned short)(pk >> 16);
        }
    }
    __syncthreads();

    // ---------------- fc1: MFMA (M=16, K=128, N=64), B from ws ----------------
    {
        const int o = wv * 16 + n;
        const float bias = fb1[(size_t)l * 64 + o];
        floatx4 a1 = (floatx4){bias, bias, bias, bias};
        const uint4v* f1q = (const uint4v*)(ws + (size_t)l * WSL + 6656);
        #pragma unroll
        for (int ks = 0; ks < 4; ++ks) {
            half8 av = *(const half8*)(U + O_POOL + n * 136 + ks * 32 + quad * 8);
            uint4v bw = f1q[o * 17 + ks * 4 + quad];
            a1 = __builtin_amdgcn_mfma_f32_16x16x32_f16(av, __builtin_bit_cast(half8, bw), a1, 0, 0, 0);
        }
        #pragma unroll
        for (int i = 0; i < 2; ++i) {
            unsigned pk = cvtpk(fmaxf(a1[2 * i], 0.f), fmaxf(a1[2 * i + 1], 0.f));
            U[O_POOL2 + (quad * 4 + 2 * i)     * 72 + o] = (unsigned short)(pk & 0xffffu);
            U[O_POOL2 + (quad * 4 + 2 * i + 1) * 72 + o] = (unsigned short)(pk >> 16);
        }
    }
    __syncthreads();

    // ---------------- fc2: MFMA (M=16, K=64, N=64), B from ws ----------------
    {
        const int o = wv * 16 + n;
        const float bias = fb2[(size_t)l * 64 + o];
        floatx4 a2 = (floatx4){bias, bias, bias, bias};
        const uint4v* f2q = (const uint4v*)(ws + (size_t)l * WSL + 15360);
        #pragma unroll
        for (int ks = 0; ks < 2; ++ks) {
            half8 av = *(const half8*)(U + O_POOL2 + n * 72 + ks * 32 + quad * 8);
            uint4v bw = f2q[o * 9 + ks * 4 + quad];
            a2 = __builtin_amdgcn_mfma_f32_16x16x32_f16(av, __builtin_bit_cast(half8, bw), a2, 0, 0, 0);
        }
        #pragma unroll
        for (int i = 0; i < 2; ++i) {
            unsigned pk = cvtpk(fmaxf(a2[2 * i], 0.f), fmaxf(a2[2 * i + 1], 0.f));
            U[O_G2 + (quad * 4 + 2 * i)     * 72 + o] = (unsigned short)(pk & 0xffffu);
            U[O_G2 + (quad * 4 + 2 * i + 1) * 72 + o] = (unsigned short)(pk >> 16);
        }
    }
    __syncthreads();

    // ---------------- fc3 (K=64) + output ----------------
    if (t < 16) {
        float a = fb3[l];
        const unsigned short* g2r = U + O_G2 + t * 72;
        #pragma unroll
        for (int c = 0; c < 64; ++c) a += hlo16(g2r[c]) * s_fw3[c];
        out[(size_t)(b0 + t) * LNUM + l] = a;
    }
}

extern "C" void kernel_launch(void* const* d_in, const int* in_sizes, int n_in,
                              void* d_out, int out_size, void* d_ws, size_t ws_size,
                              hipStream_t stream) {
    const float* zs  = (const float*)d_in[0];
    const float* w1  = (const float*)d_in[1];
    const float* w2  = (const float*)d_in[2];
    const float* fw1 = (const float*)d_in[3];
    const float* fb1 = (const float*)d_in[4];
    const float* fw2 = (const float*)d_in[5];
    const float* fb2 = (const float*)d_in[6];
    const float* fw3 = (const float*)d_in[7];
    const float* fb3 = (const float*)d_in[8];
    float* out = (float*)d_out;
    unsigned short* ws = (unsigned short*)d_ws;

    hipLaunchKernelGGL(prep, dim3(LNUM), dim3(256), 0, stream, w2, fw1, fw2, ws);
    hipLaunchKernelGGL(fused_nn, dim3(LNUM * NBT), dim3(256), 0, stream,
                       zs, w1, fb1, fb2, fw3, fb3, ws, out);
}

// Round 7
// 137.295 us; speedup vs baseline: 4.7768x; 1.0081x over previous
//
#include <hip/hip_runtime.h>

// TwelveSitesNN2 R5: LDS-pipe diet. zs/w1/fw3 read direct from global (VMEM),
// h2/pool on b64 DS ops, pooled mean/max interleaved along k (fw1T reordered in
// prep to match). 6 barriers (was 11). LDS 37.7KB -> 4 blocks/CU.

#define LNUM 63
#define BT 16
#define NBT 128   // 2048 / BT
#define WSL 19968 // ushorts per l in ws: [w2T 64x104][fw1T 64x136][fw2T 64x72] (f16)

typedef __attribute__((ext_vector_type(8))) _Float16 half8;
typedef __attribute__((ext_vector_type(2))) _Float16 half2v;
typedef __attribute__((ext_vector_type(4))) float floatx4;
typedef __attribute__((ext_vector_type(4))) unsigned uint4v;

static __device__ __forceinline__ unsigned cvtpk(float a, float b) {
    return __builtin_bit_cast(unsigned, __builtin_amdgcn_cvt_pkrtz(a, b));  // 1 VALU op
}
static __device__ __forceinline__ half2v u2h(unsigned u) { return __builtin_bit_cast(half2v, u); }
static __device__ __forceinline__ unsigned h2u(half2v h) { return __builtin_bit_cast(unsigned, h); }
static __device__ __forceinline__ half2v hmax2(half2v a, half2v b) {
    half2v r;
    r[0] = a[0] > b[0] ? a[0] : b[0];
    r[1] = a[1] > b[1] ? a[1] : b[1];
    return r;
}
static __device__ __forceinline__ float hlo16(unsigned short s) {
    return (float)__builtin_bit_cast(_Float16, s);
}
static __device__ __forceinline__ int w12(int v) { return v >= 12 ? v - 12 : v; }
static __device__ __forceinline__ float2 add2(float2 a, float2 b) { return make_float2(a.x + b.x, a.y + b.y); }

// LDS layout (U, 18816 ushorts = 37632 B):
//   phase1 : A2 [192][96] f16, XOR-swizzled 16B granules (granule ^= s&3)
//   phase2 : h2T [64 o][260] f16 (per o: [16 b][16ush], 12 used) @0
//            pooled [16 b][136] @16640  (k' = 2c interleaved mean/max)
//   phase3 : pool2 [16][72] @0 ; g2 [16][72] @1280
#define H2S    130      // h2T o-stride in dwords
#define O_POOL 16640
#define O_POOL2 0
#define O_G2   1280

__global__ void prep(const float* __restrict__ w2, const float* __restrict__ fw1,
                     const float* __restrict__ fw2, unsigned short* __restrict__ ws) {
    const int l = blockIdx.x, t = threadIdx.x;
    const int o = t & 63, g = t >> 6;
    if (blockIdx.y == 0) {
        // w2 -> w2T f16 [o][cpair], row stride 52 dwords
        unsigned* w2t = (unsigned*)(ws + (size_t)l * WSL);
        const float* w2l = w2 + (size_t)l * 6144;
        #pragma unroll
        for (int i = 0; i < 12; ++i) {
            int cp = g + 4 * i, c = 2 * cp;
            w2t[o * 52 + cp] = cvtpk(w2l[c * 64 + o], w2l[(c + 1) * 64 + o]);
        }
    } else {
        // fw1 -> fw1T f16 [o][cp'] with k' interleaving: dword cp' = (mean_w[cp'], max_w[cp'])
        unsigned* f1t = (unsigned*)(ws + (size_t)l * WSL + 6656);
        const float* f1l = fw1 + (size_t)l * 8192;
        #pragma unroll
        for (int i = 0; i < 16; ++i) {
            int cp = g + 4 * i;
            f1t[o * 68 + cp] = cvtpk(f1l[cp * 64 + o], f1l[(64 + cp) * 64 + o]);
        }
        unsigned* f2t = (unsigned*)(ws + (size_t)l * WSL + 15360);
        const float* f2l = fw2 + (size_t)l * 4096;
        #pragma unroll
        for (int i = 0; i < 8; ++i) {
            int cp = g + 4 * i, c = 2 * cp;
            f2t[o * 36 + cp] = cvtpk(f2l[c * 64 + o], f2l[(c + 1) * 64 + o]);
        }
    }
}

__global__ __launch_bounds__(256, 4) void fused_nn(
    const float* __restrict__ zs,  const float* __restrict__ w1,
    const float* __restrict__ fb1, const float* __restrict__ fb2,
    const float* __restrict__ fw3, const float* __restrict__ fb3,
    const unsigned short* __restrict__ ws,
    float* __restrict__ out)
{
    __shared__ __align__(16) unsigned short U[18816];

    const int t    = threadIdx.x;
    const int lane = t & 63;
    const int wv   = t >> 6;
    const int n    = lane & 15;
    const int quad = lane >> 4;
    const int l    = blockIdx.x / NBT;
    const int b0   = (blockIdx.x % NBT) * BT;

    // ---------------- layer 1 + neighbor sums, thread-local (global inputs) ----------------
    {
        const int b = t >> 4, cpair = t & 15, c0 = cpair * 2;
        const float* xb = zs + ((size_t)(b0 + b) * LNUM + l) * 24;
        float4 xq[6];
        #pragma unroll
        for (int q = 0; q < 6; ++q) xq[q] = *(const float4*)(xb + q * 4);
        float2 xv[12], xr[12], xA[12], xB[12];
        #pragma unroll
        for (int s = 0; s < 12; ++s)
            xv[s] = (s & 1) ? make_float2(xq[s >> 1].z, xq[s >> 1].w)
                            : make_float2(xq[s >> 1].x, xq[s >> 1].y);
        #pragma unroll
        for (int s = 0; s < 12; ++s) xr[s] = add2(xv[w12(s + 1)], xv[w12(s + 11)]);
        #pragma unroll
        for (int s = 0; s < 12; ++s) {
            xA[s] = add2(xr[w12(s + 2)], xr[w12(s + 10)]);
            xB[s] = add2(xr[w12(s + 3)], xr[w12(s + 9)]);
        }
        const float* wl = w1 + (size_t)l * 192 + c0;
        const float2 w0  = *(const float2*)(wl);
        const float2 w1v = *(const float2*)(wl + 32);
        const float2 w2v = *(const float2*)(wl + 64);
        const float2 w3v = *(const float2*)(wl + 96);
        const float2 w4v = *(const float2*)(wl + 128);
        const float2 w5v = *(const float2*)(wl + 160);
        unsigned hp[12];
        #pragma unroll
        for (int s = 0; s < 12; ++s) {
            float hx = xv[s].x*w0.x + xv[s].y*w1v.x + xA[s].x*w2v.x + xA[s].y*w3v.x
                     + xB[s].x*w4v.x + xB[s].y*w5v.x;
            float hy = xv[s].x*w0.y + xv[s].y*w1v.y + xA[s].x*w2v.y + xA[s].y*w3v.y
                     + xB[s].x*w4v.y + xB[s].y*w5v.y;
            hp[s] = cvtpk(fmaxf(hx, 0.f), fmaxf(hy, 0.f));
        }
        half2v hh[12], hr[12];
        #pragma unroll
        for (int s = 0; s < 12; ++s) hh[s] = u2h(hp[s]);
        #pragma unroll
        for (int s = 0; s < 12; ++s) hr[s] = hh[w12(s + 1)] + hh[w12(s + 11)];
        unsigned* dwU = (unsigned*)U;
        const int g = cpair >> 2, jj = cpair & 3;
        #pragma unroll
        for (int s = 0; s < 12; ++s) {
            half2v hA = hr[w12(s + 2)] + hr[w12(s + 10)];
            half2v hB = hr[w12(s + 3)] + hr[w12(s + 9)];
            const int row = b * 12 + s;
            const int base = row * 48 + ((g ^ (s & 3)) << 2) + jj;  // swizzled granule
            dwU[base]      = hp[s];
            dwU[base + 16] = h2u(hA);
            dwU[base + 32] = h2u(hB);
        }
    }
    __syncthreads();

    // ---------------- layer 2: MFMA f16 (M=192, K=96, N=64), B-frags from ws ----------------
    floatx4 acc[3][4];
    #pragma unroll
    for (int mi = 0; mi < 3; ++mi)
        #pragma unroll
        for (int nt = 0; nt < 4; ++nt) acc[mi][nt] = (floatx4){0.f, 0.f, 0.f, 0.f};
    {
        half8 af[3][3];
        const int sw = (quad ^ (n & 3)) * 8;
        #pragma unroll
        for (int mi = 0; mi < 3; ++mi) {
            const int row = (3 * wv + mi) * 16 + n;
            #pragma unroll
            for (int ks = 0; ks < 3; ++ks)
                af[mi][ks] = *(const half8*)(U + row * 96 + ks * 32 + sw);
        }
        const uint4v* w2q = (const uint4v*)(ws + (size_t)l * WSL);
        #pragma unroll
        for (int ks = 0; ks < 3; ++ks) {
            uint4v bw[4];
            #pragma unroll
            for (int nt = 0; nt < 4; ++nt)
                bw[nt] = w2q[(nt * 16 + n) * 13 + ks * 4 + quad];
            #pragma unroll
            for (int mi = 0; mi < 3; ++mi)
                #pragma unroll
                for (int nt = 0; nt < 4; ++nt)
                    acc[mi][nt] = __builtin_amdgcn_mfma_f32_16x16x32_f16(
                        af[mi][ks], __builtin_bit_cast(half8, bw[nt]), acc[mi][nt], 0, 0, 0);
        }
    }
    __syncthreads();   // all A2 reads done -> safe to overlay

    // ---------------- h2 -> h2T [o][b][16ush], 12 ds_write_b64 ----------------
    #pragma unroll
    for (int mi = 0; mi < 3; ++mi) {
        const int r0g  = (3 * wv + mi) * 16 + quad * 4;   // 4 rows, same b (r0g % 12 in {0,4,8})
        const int bidx = r0g / 12;
        const int s0   = r0g - bidx * 12;
        const int dbase = bidx * 8 + (s0 >> 1);
        #pragma unroll
        for (int nt = 0; nt < 4; ++nt) {
            const int o = nt * 16 + n;
            uint2 v;
            v.x = cvtpk(fmaxf(acc[mi][nt][0], 0.f), fmaxf(acc[mi][nt][1], 0.f));
            v.y = cvtpk(fmaxf(acc[mi][nt][2], 0.f), fmaxf(acc[mi][nt][3], 0.f));
            *(uint2*)((unsigned*)U + o * H2S + dbase) = v;
        }
    }
    __syncthreads();

    // ---------------- pool: mean+max over s; write k'-interleaved (mean,max) ----------------
    {
        const int o = lane;
        #pragma unroll
        for (int bb = 0; bb < 4; ++bb) {
            const int b = wv * 4 + bb;
            const unsigned* src = (const unsigned*)U + o * H2S + b * 8;
            uint2 p0 = *(const uint2*)(src);
            uint2 p1 = *(const uint2*)(src + 2);
            uint2 p2 = *(const uint2*)(src + 4);
            half2v v0 = u2h(p0.x), v1 = u2h(p0.y), v2 = u2h(p1.x);
            half2v v3 = u2h(p1.y), v4 = u2h(p2.x), v5 = u2h(p2.y);
            half2v sm = ((v0 + v1) + (v2 + v3)) + (v4 + v5);
            half2v mx = hmax2(hmax2(hmax2(v0, v1), hmax2(v2, v3)), hmax2(v4, v5));
            float s = (float)sm[0] + (float)sm[1];
            float m = fmaxf((float)mx[0], (float)mx[1]);
            ((unsigned*)U)[O_POOL / 2 + b * 68 + o] = cvtpk(s * (1.f / 12.f), m);
        }
    }
    __syncthreads();

    // ---------------- fc1: MFMA (M=16, K=128, N=64), B from ws (k'-reordered) ----------------
    {
        const int o = wv * 16 + n;
        const float bias = fb1[(size_t)l * 64 + o];
        floatx4 a1 = (floatx4){bias, bias, bias, bias};
        const uint4v* f1q = (const uint4v*)(ws + (size_t)l * WSL + 6656);
        #pragma unroll
        for (int ks = 0; ks < 4; ++ks) {
            half8 av = *(const half8*)(U + O_POOL + n * 136 + ks * 32 + quad * 8);
            uint4v bw = f1q[o * 17 + ks * 4 + quad];
            a1 = __builtin_amdgcn_mfma_f32_16x16x32_f16(av, __builtin_bit_cast(half8, bw), a1, 0, 0, 0);
        }
        __syncthreads();   // pooled reads done; safe to overlay low region
        #pragma unroll
        for (int i = 0; i < 2; ++i) {
            unsigned pk = cvtpk(fmaxf(a1[2 * i], 0.f), fmaxf(a1[2 * i + 1], 0.f));
            U[O_POOL2 + (quad * 4 + 2 * i)     * 72 + o] = (unsigned short)(pk & 0xffffu);
            U[O_POOL2 + (quad * 4 + 2 * i + 1) * 72 + o] = (unsigned short)(pk >> 16);
        }
    }
    __syncthreads();

    // ---------------- fc2: MFMA (M=16, K=64, N=64), B from ws ----------------
    {
        const int o = wv * 16 + n;
        const float bias = fb2[(size_t)l * 64 + o];
        floatx4 a2 = (floatx4){bias, bias, bias, bias};
        const uint4v* f2q = (const uint4v*)(ws + (size_t)l * WSL + 15360);
        #pragma unroll
        for (int ks = 0; ks < 2; ++ks) {
            half8 av = *(const half8*)(U + O_POOL2 + n * 72 + ks * 32 + quad * 8);
            uint4v bw = f2q[o * 9 + ks * 4 + quad];
            a2 = __builtin_amdgcn_mfma_f32_16x16x32_f16(av, __builtin_bit_cast(half8, bw), a2, 0, 0, 0);
        }
        #pragma unroll
        for (int i = 0; i < 2; ++i) {
            unsigned pk = cvtpk(fmaxf(a2[2 * i], 0.f), fmaxf(a2[2 * i + 1], 0.f));
            U[O_G2 + (quad * 4 + 2 * i)     * 72 + o] = (unsigned short)(pk & 0xffffu);
            U[O_G2 + (quad * 4 + 2 * i + 1) * 72 + o] = (unsigned short)(pk >> 16);
        }
    }
    __syncthreads();

    // ---------------- fc3 (K=64) + output ----------------
    if (t < 16) {
        float a = fb3[l];
        const float* w3 = fw3 + (size_t)l * 64;
        #pragma unroll
        for (int c4 = 0; c4 < 16; ++c4) {
            uint2 u2 = *(const uint2*)(U + O_G2 + t * 72 + c4 * 4);
            float4 w = *(const float4*)(w3 + c4 * 4);
            a += hlo16((unsigned short)(u2.x & 0xffff)) * w.x
               + hlo16((unsigned short)(u2.x >> 16))    * w.y
               + hlo16((unsigned short)(u2.y & 0xffff)) * w.z
               + hlo16((unsigned short)(u2.y >> 16))    * w.w;
        }
        out[(size_t)(b0 + t) * LNUM + l] = a;
    }
}

extern "C" void kernel_launch(void* const* d_in, const int* in_sizes, int n_in,
                              void* d_out, int out_size, void* d_ws, size_t ws_size,
                              hipStream_t stream) {
    const float* zs  = (const float*)d_in[0];
    const float* w1  = (const float*)d_in[1];
    const float* w2  = (const float*)d_in[2];
    const float* fw1 = (const float*)d_in[3];
    const float* fb1 = (const float*)d_in[4];
    const float* fw2 = (const float*)d_in[5];
    const float* fb2 = (const float*)d_in[6];
    const float* fw3 = (const float*)d_in[7];
    const float* fb3 = (const float*)d_in[8];
    float* out = (float*)d_out;
    unsigned short* ws = (unsigned short*)d_ws;

    hipLaunchKernelGGL(prep, dim3(LNUM, 2), dim3(256), 0, stream, w2, fw1, fw2, ws);
    hipLaunchKernelGGL(fused_nn, dim3(LNUM * NBT), dim3(256), 0, stream,
                       zs, w1, fb1, fb2, fw3, fb3, ws, out);
}